// Round 11
// baseline (245.819 us; speedup 1.0000x reference)
//
#include <hip/hip_runtime.h>
#include <hip/hip_bf16.h>
#include <hip/hip_fp16.h>

typedef __hip_bfloat16 bf16;
typedef unsigned int u32;
typedef unsigned short u16;
typedef unsigned long long u64;

constexpr int N   = 50000;
constexpr int E   = 1600000;
constexpr int C   = 128;             // channels (H * 32)
constexpr int H   = 4;               // heads
constexpr int NB  = 782;             // dst buckets of 64 nodes (782*64 >= 50000)
constexpr int CAP = 2560;            // pairs capacity per bucket (mean 2048, +11 sigma)
constexpr int CHUNK = 4096;          // edges per kbin block
constexpr float NEG  = 0.2f;
constexpr float SEPS = 1e-16f;
constexpr float LEPS = 1e-5f;

__device__ __forceinline__ float lo16(u32 v) { return __uint_as_float(v << 16); }
__device__ __forceinline__ float hi16(u32 v) { return __uint_as_float(v & 0xFFFF0000u); }

// K1: h = x @ W, 16 nodes per block. x tile in LDS; W from global (L1/L2-hot).
// h stored bf16. Fused attention dots a_s, a_d.
__global__ __launch_bounds__(256) void k1_gemm(
    const float* __restrict__ x, const float* __restrict__ W,
    const float* __restrict__ att_s, const float* __restrict__ att_d,
    bf16* __restrict__ hb, float* __restrict__ as_, float* __restrict__ ad_)
{
    const int nb = blockIdx.x * 16;
    const int t  = threadIdx.x;
    __shared__ float sx[16 * 128];
    const float4* xg = (const float4*)(x + nb * 128);
    ((float4*)sx)[t]       = xg[t];
    ((float4*)sx)[t + 256] = xg[t + 256];
    __syncthreads();

    const int c = t & 127;           // output channel
    const int g = t >> 7;            // node group (0/1) of 8 nodes
    const float* xb = sx + (g << 10);
    float acc[8] = {0.f, 0.f, 0.f, 0.f, 0.f, 0.f, 0.f, 0.f};

    for (int k = 0; k < 128; k += 4) {
        const float w0 = W[(k + 0) * 128 + c];
        const float w1 = W[(k + 1) * 128 + c];
        const float w2 = W[(k + 2) * 128 + c];
        const float w3 = W[(k + 3) * 128 + c];
#pragma unroll
        for (int j = 0; j < 8; ++j) {
            const float4 xv = *(const float4*)(xb + j * 128 + k);
            acc[j] = fmaf(xv.x, w0, fmaf(xv.y, w1, fmaf(xv.z, w2, fmaf(xv.w, w3, acc[j]))));
        }
    }

    const int lane = t & 63;
    const int head = c >> 5;
    const float asc = att_s[c], adc = att_d[c];
#pragma unroll
    for (int j = 0; j < 8; ++j) {
        const int node = nb + (g << 3) + j;
        hb[node * 128 + c] = __float2bfloat16(acc[j]);
        float vs = acc[j] * asc;
        float vd = acc[j] * adc;
#pragma unroll
        for (int off = 16; off; off >>= 1) {
            vs += __shfl_xor(vs, off, 64);
            vd += __shfl_xor(vd, off, 64);
        }
        if ((lane & 31) == 0) {
            as_[node * H + head] = vs;
            ad_[node * H + head] = vd;
        }
    }
}

// KBIN: bin edges into NB dst-buckets as packed u32 (src | (dst&63)<<16).
// Two-phase per chunk: LDS int count -> global reserve -> scatter.
// dst cached in LDS between phases (one fewer global pass).
__global__ __launch_bounds__(256) void kbin(
    const int* __restrict__ ei, u32* __restrict__ gcur, u32* __restrict__ pairs)
{
    __shared__ u32 lcnt[NB], lbase[NB], lfill[NB];
    __shared__ u16 dstl[CHUNK];
    const int t = threadIdx.x;
    const int base = blockIdx.x * CHUNK;
    const int nE = min(CHUNK, E - base);
    for (int i = t; i < NB; i += 256) lcnt[i] = 0;
    __syncthreads();
    for (int i = t; i < nE; i += 256) {
        u32 d = (u32)ei[E + base + i];
        dstl[i] = (u16)d;
        atomicAdd(&lcnt[d >> 6], 1u);
    }
    __syncthreads();
    for (int i = t; i < NB; i += 256) {
        u32 cb = lcnt[i];
        lbase[i] = cb ? atomicAdd(&gcur[i], cb) : 0u;
        lfill[i] = 0u;
    }
    __syncthreads();
    for (int i = t; i < nE; i += 256) {
        u32 src = (u32)ei[base + i];
        u32 dst = (u32)dstl[i];
        u32 b = dst >> 6;
        u32 pos = atomicAdd(&lfill[b], 1u);
        pairs[(size_t)b * CAP + lbase[b] + pos] = src | ((dst & 63u) << 16);
    }
}

// KFILL2: block per bucket. Bucket base via L2-hot scan of gcur, per-node
// count + wave scan -> row_ptr, then scatter: u16 col AND precomputed
// per-(edge,head) softmax weights w = exp(leaky(as[src]+ad[dst])) as f16x4.
__global__ __launch_bounds__(256) void kfill2(
    const u32* __restrict__ pairs, const u32* __restrict__ gcur,
    const float4* __restrict__ as4, const float4* __restrict__ ad4,
    int* __restrict__ row_ptr, u16* __restrict__ col, __half* __restrict__ whf)
{
    __shared__ int jcnt[64], joff[64], jcur[64];
    __shared__ float4 adl[64];
    __shared__ u32 ssum[4];
    const int b = blockIdx.x, t = threadIdx.x;
    const int wave = t >> 6, lane = t & 63;
    const int cntb = (int)gcur[b];

    // bucket base = sum of gcur[0..b)
    u32 part = 0;
    for (int i = t; i < b; i += 256) part += gcur[i];
#pragma unroll
    for (int off = 32; off; off >>= 1) part += __shfl_xor(part, off, 64);
    if (lane == 0) ssum[wave] = part;
    if (t < 64) {
        jcnt[t] = 0;
        const int n = b * 64 + t;
        adl[t] = (n < N) ? ad4[n] : make_float4(0.f, 0.f, 0.f, 0.f);
    }
    if (b == 0 && t == 255) row_ptr[N] = E;
    __syncthreads();
    const int base = (int)(ssum[0] + ssum[1] + ssum[2] + ssum[3]);

    const u32* pr = pairs + (size_t)b * CAP;
    for (int i = t; i < cntb; i += 256) atomicAdd(&jcnt[pr[i] >> 16], 1);
    __syncthreads();
    if (t < 64) {
        int v = jcnt[t], incl = v;
#pragma unroll
        for (int off = 1; off < 64; off <<= 1) {
            int u = __shfl_up(incl, off, 64);
            if (t >= off) incl += u;
        }
        joff[t] = incl - v;
        const int n = b * 64 + t;
        if (n < N) row_ptr[n] = base + joff[t];
        jcur[t] = 0;
    }
    __syncthreads();
    for (int i = t; i < cntb; i += 256) {
        const u32 p = pr[i];
        const int j = p >> 16;
        const u32 s = p & 0xFFFFu;
        const int pos = atomicAdd(&jcur[j], 1);
        const int idx = base + joff[j] + pos;
        col[idx] = (u16)s;
        const float4 a = as4[s];
        const float4 d = adl[j];
        float l0 = a.x + d.x, l1 = a.y + d.y, l2 = a.z + d.z, l3 = a.w + d.w;
        l0 = fmaxf(l0, NEG * l0); l1 = fmaxf(l1, NEG * l1);
        l2 = fmaxf(l2, NEG * l2); l3 = fmaxf(l3, NEG * l3);
        __half2 w01; w01.x = __float2half(__expf(l0)); w01.y = __float2half(__expf(l1));
        __half2 w23; w23.x = __float2half(__expf(l2)); w23.y = __float2half(__expf(l3));
        *(__half2*)(whf + (size_t)idx * 4)     = w01;
        *(__half2*)(whf + (size_t)idx * 4 + 2) = w23;
    }
}

// KD: fused aggregation + bias + LayerNorm + ELU -> f32 out.
// One wave per node; weights precomputed (no exp/leaky here); 8-wide ILP.
__global__ __launch_bounds__(256) void kd_agg_ln(
    const int* __restrict__ row_ptr, const u16* __restrict__ col,
    const __half* __restrict__ whf, const u32* __restrict__ hb,
    const float* __restrict__ as_, const float* __restrict__ ad_,
    const float* __restrict__ bias, const float* __restrict__ gamma,
    const float* __restrict__ beta, float* __restrict__ out)
{
    int gid = blockIdx.x * blockDim.x + threadIdx.x;
    int n = gid >> 6;
    if (n >= N) return;
    const int lane = gid & 63;
    const int head = lane >> 4;

    // self-loop term (src == dst == n), computed here once per node
    float l = as_[n * H + head] + ad_[n * H + head];
    l = fmaxf(l, NEG * l);
    float w = __expf(l);
    float den = w;
    u32 hv = hb[n * 64 + lane];
    float num0 = w * lo16(hv);
    float num1 = w * hi16(hv);

    int k = row_ptr[n];
    const int end = row_ptr[n + 1];
    for (; k + 8 <= end; k += 8) {
        int   s[8]; float ww[8]; u32 v[8];
#pragma unroll
        for (int i = 0; i < 8; ++i) s[i] = col[k + i];
#pragma unroll
        for (int i = 0; i < 8; ++i) ww[i] = __half2float(whf[(size_t)(k + i) * 4 + head]);
#pragma unroll
        for (int i = 0; i < 8; ++i) v[i] = hb[s[i] * 64 + lane];
#pragma unroll
        for (int i = 0; i < 8; ++i) {
            den += ww[i];
            num0 = fmaf(ww[i], lo16(v[i]), num0);
            num1 = fmaf(ww[i], hi16(v[i]), num1);
        }
    }
    for (; k < end; ++k) {
        const int s = col[k];
        const float ws = __half2float(whf[(size_t)k * 4 + head]);
        const u32 vs = hb[s * 64 + lane];
        den += ws;
        num0 = fmaf(ws, lo16(vs), num0);
        num1 = fmaf(ws, hi16(vs), num1);
    }

    const int c0 = lane * 2;
    const float inv_den = 1.f / (den + SEPS);
    float v0 = num0 * inv_den + bias[c0];
    float v1 = num1 * inv_den + bias[c0 + 1];

    float sum = v0 + v1;
#pragma unroll
    for (int off = 32; off; off >>= 1) sum += __shfl_xor(sum, off, 64);
    const float mu = sum * (1.0f / C);
    const float d0 = v0 - mu, d1 = v1 - mu;
    float sq = d0 * d0 + d1 * d1;
#pragma unroll
    for (int off = 32; off; off >>= 1) sq += __shfl_xor(sq, off, 64);
    const float inv = rsqrtf(sq * (1.0f / C) + LEPS);
    float y0 = d0 * inv * gamma[c0]     + beta[c0];
    float y1 = d1 * inv * gamma[c0 + 1] + beta[c0 + 1];
    y0 = y0 > 0.f ? y0 : __expf(y0) - 1.f;
    y1 = y1 > 0.f ? y1 : __expf(y1) - 1.f;
    float2 o; o.x = y0; o.y = y1;
    *(float2*)(out + (size_t)n * C + c0) = o;
}

extern "C" void kernel_launch(void* const* d_in, const int* in_sizes, int n_in,
                              void* d_out, int out_size, void* d_ws, size_t ws_size,
                              hipStream_t stream)
{
    const float* x     = (const float*)d_in[0];
    const int*   ei    = (const int*)  d_in[1];
    const float* W     = (const float*)d_in[2];
    const float* att_s = (const float*)d_in[3];
    const float* att_d = (const float*)d_in[4];
    const float* bias  = (const float*)d_in[5];
    const float* gamma = (const float*)d_in[6];
    const float* beta  = (const float*)d_in[7];
    float* out = (float*)d_out;

    // ws (~39 MB): hb bf16[N*C] | as_ f32[N*H] | ad_ f32[N*H] | pairs u32[NB*CAP]
    //            | col u16[E] | whf f16[E*4] | row_ptr int[N+1] | gcur u32[NB]
    char* p = (char*)d_ws;
    bf16*   hb      = (bf16*)p;   p += (size_t)N * C * sizeof(bf16);
    float*  as_     = (float*)p;  p += (size_t)N * H * sizeof(float);
    float*  ad_     = (float*)p;  p += (size_t)N * H * sizeof(float);
    u32*    pairs   = (u32*)p;    p += (size_t)NB * CAP * sizeof(u32);
    u16*    col     = (u16*)p;    p += ((size_t)E * sizeof(u16) + 15) & ~(size_t)15;
    __half* whf     = (__half*)p; p += (size_t)E * 4 * sizeof(__half);
    int*    row_ptr = (int*)p;    p += ((size_t)(N + 1) * sizeof(int) + 15) & ~(size_t)15;
    u32*    gcur    = (u32*)p;

    hipMemsetAsync(gcur, 0, NB * sizeof(u32), stream);
    k1_gemm<<<N / 16, 256, 0, stream>>>(x, W, att_s, att_d, hb, as_, ad_);
    kbin<<<(E + CHUNK - 1) / CHUNK, 256, 0, stream>>>(ei, gcur, pairs);
    kfill2<<<NB, 256, 0, stream>>>(pairs, gcur, (const float4*)as_,
                                   (const float4*)ad_, row_ptr, col, whf);
    kd_agg_ln<<<(N * 64) / 256, 256, 0, stream>>>(
        row_ptr, col, whf, (const u32*)hb, as_, ad_, bias, gamma, beta, out);
}